// Round 7
// baseline (579.321 us; speedup 1.0000x reference)
//
#include <hip/hip_runtime.h>
#include <math.h>

#define N_NODES 100000
#define N_EDGES 3200000
#define F_IN    512
#define H1      16
#define H2      40

#define NB      391      // coarse buckets: dst >> 8, 256 nodes each
#define BSH     8
#define BMASK   255
#define B1      512      // phase-1/2 blocks
#define EPB     6250     // edges per block (512*6250 = 3.2M exactly)

// ---------------------------------------------------------------------------
// Detect edge_index dtype: int64 (high int32 words all zero) vs int32.
__global__ void detect_idx_kernel(const int* __restrict__ ei, int* __restrict__ flag)
{
    if (threadIdx.x == 0 && blockIdx.x == 0) {
        int all_zero = 1;
        for (int i = 0; i < 64; ++i)
            if (ei[2 * i + 1] != 0) { all_zero = 0; break; }
        *flag = all_zero;  // 1 => int64 layout, 0 => int32 layout
    }
}

__device__ __forceinline__ int edge_src(const void* ei, int e, int is64)
{
    return is64 ? (int)((const long long*)ei)[e] : ((const int*)ei)[e];
}
__device__ __forceinline__ int edge_dst(const void* ei, int e, int is64)
{
    return is64 ? (int)((const long long*)ei)[N_EDGES + e]
                : ((const int*)ei)[N_EDGES + e];
}

// ---------------------------------------------------------------------------
// Phase 1: per-block coarse-bucket histogram (LDS atomics only).
__global__ __launch_bounds__(256) void hist_kernel(
    const void* __restrict__ ei, const int* __restrict__ flag,
    int* __restrict__ cntoff)
{
    __shared__ int h[NB];
    for (int i = threadIdx.x; i < NB; i += 256) h[i] = 0;
    __syncthreads();
    const int is64 = *flag;
    const int e0 = blockIdx.x * EPB;
    for (int i = threadIdx.x; i < EPB; i += 256) {
        int e = e0 + i;
        if (e < N_EDGES) atomicAdd(&h[edge_dst(ei, e, is64) >> BSH], 1);
    }
    __syncthreads();
    for (int i = threadIdx.x; i < NB; i += 256)
        cntoff[blockIdx.x * NB + i] = h[i];
}

// ---------------------------------------------------------------------------
// Phase 1b: per-bucket exclusive scan over the 512 blocks (one wave/bucket).
__global__ __launch_bounds__(256) void scanblk_kernel(
    int* __restrict__ cntoff, int* __restrict__ bstart)
{
    const int lane   = threadIdx.x & 63;
    const int bucket = blockIdx.x * 4 + (threadIdx.x >> 6);
    if (bucket >= NB) return;
    int run = 0;
    #pragma unroll
    for (int c = 0; c < B1 / 64; ++c) {
        const int i = c * 64 + lane;
        const int v = cntoff[i * NB + bucket];
        int s = v;
        #pragma unroll
        for (int off = 1; off < 64; off <<= 1) {
            int t = __shfl_up(s, off, 64);
            if (lane >= off) s += t;
        }
        cntoff[i * NB + bucket] = run + (s - v);   // exclusive within bucket
        run += __shfl(s, 63, 64);
    }
    if (lane == 0) bstart[bucket] = run;
}

// Phase 1c: exclusive scan of the NB bucket totals.
__global__ __launch_bounds__(512) void scanb_kernel(int* __restrict__ bstart)
{
    __shared__ int s[512];
    const int t = threadIdx.x;
    const int v = (t < NB) ? bstart[t] : 0;
    s[t] = v;
    __syncthreads();
    for (int off = 1; off < 512; off <<= 1) {
        int tv = (t >= off) ? s[t - off] : 0;
        __syncthreads();
        s[t] += tv;
        __syncthreads();
    }
    if (t < NB) bstart[t] = s[t] - v;              // exclusive
    if (t == NB - 1) bstart[NB] = s[t];            // total == N_EDGES
}

// ---------------------------------------------------------------------------
// Phase 2: scatter edges into bucket-sorted packed array (LDS cursors only).
// packed = (src << 8) | (dst & 255); src < 2^17 fits easily.
__global__ __launch_bounds__(256) void scatter_bucket_kernel(
    const void* __restrict__ ei, const int* __restrict__ flag,
    const int* __restrict__ cntoff, const int* __restrict__ bstart,
    int* __restrict__ packed)
{
    __shared__ int cur[NB];
    for (int i = threadIdx.x; i < NB; i += 256)
        cur[i] = cntoff[blockIdx.x * NB + i] + bstart[i];
    __syncthreads();
    const int is64 = *flag;
    const int e0 = blockIdx.x * EPB;
    for (int i = threadIdx.x; i < EPB; i += 256) {
        int e = e0 + i;
        if (e >= N_EDGES) break;
        const int s = edge_src(ei, e, is64);
        const int d = edge_dst(ei, e, is64);
        const int b = d >> BSH;
        const int pos = atomicAdd(&cur[b], 1);
        packed[pos] = (s << BSH) | (d & BMASK);
    }
}

// ---------------------------------------------------------------------------
// Phase 3: one block per bucket (256 nodes); fine CSR via LDS hist+scan+scatter.
// row_end[g] = inclusive global prefix; beg(g) = row_end[g-1].
__global__ __launch_bounds__(512) void bucket_csr_kernel(
    const int* __restrict__ packed, const int* __restrict__ bstart,
    int* __restrict__ deg, int* __restrict__ row_end, int* __restrict__ csr)
{
    __shared__ int hist[256];
    __shared__ int off[256];
    const int b    = blockIdx.x;
    const int tid  = threadIdx.x;
    const int base = bstart[b];
    const int m    = bstart[b + 1] - base;

    if (tid < 256) hist[tid] = 0;
    __syncthreads();
    for (int i = tid; i < m; i += 512)
        atomicAdd(&hist[packed[base + i] & BMASK], 1);
    __syncthreads();

    int v = 0;
    if (tid < 256) { v = hist[tid]; off[tid] = v; }
    __syncthreads();
    for (int o = 1; o < 256; o <<= 1) {
        int t2 = 0;
        if (tid < 256 && tid >= o) t2 = off[tid - o];
        __syncthreads();
        if (tid < 256) off[tid] += t2;
        __syncthreads();
    }
    if (tid < 256) {
        const int g = (b << BSH) + tid;
        if (g < N_NODES) { deg[g] = v; row_end[g] = base + off[tid]; }
        off[tid] -= v;                              // exclusive, reuse as cursor
    }
    __syncthreads();
    for (int i = tid; i < m; i += 512) {
        const int p = packed[base + i];
        const int pos = atomicAdd(&off[p & BMASK], 1);
        csr[base + pos] = p >> BSH;
    }
}

// ---------------------------------------------------------------------------
// hs1[r][j] = (x[r] @ W1)[j] * dis[r];  dis[r] = rsqrt(deg[r]+1)
// 2 rows/thread, k blocked by 32: all 8 x float4-loads issued up front
// (8-deep MLP, each 128B line fully consumed in-block), W amortized 2x.
__global__ __launch_bounds__(128) void gemm1_kernel(
    const float* __restrict__ x, const float* __restrict__ W1,
    const int* __restrict__ deg, float* __restrict__ hs1,
    float* __restrict__ dis, int n)
{
    const int t  = blockIdx.x * 128 + threadIdx.x;
    const int r0 = 2 * t;
    if (r0 >= n) return;
    const int r1 = r0 + 1;                          // n even -> valid
    const float4* xa = (const float4*)(x + (size_t)r0 * F_IN);
    const float4* xb = (const float4*)(x + (size_t)r1 * F_IN);

    float acca[H1], accb[H1];
    #pragma unroll
    for (int j = 0; j < H1; ++j) { acca[j] = 0.f; accb[j] = 0.f; }

    for (int kb = 0; kb < F_IN / 4; kb += 4) {
        float4 va[4], vb[4];
        #pragma unroll
        for (int u = 0; u < 4; ++u) va[u] = xa[kb + u];
        #pragma unroll
        for (int u = 0; u < 4; ++u) vb[u] = xb[kb + u];
        #pragma unroll
        for (int u = 0; u < 4; ++u) {
            const float* wk = W1 + (size_t)(kb + u) * 4 * H1;
            #pragma unroll
            for (int j = 0; j < H1; ++j) {
                const float w0 = wk[j];
                const float w1 = wk[H1 + j];
                const float w2 = wk[2 * H1 + j];
                const float w3 = wk[3 * H1 + j];
                acca[j] += va[u].x * w0 + va[u].y * w1 + va[u].z * w2 + va[u].w * w3;
                accb[j] += vb[u].x * w0 + vb[u].y * w1 + vb[u].z * w2 + vb[u].w * w3;
            }
        }
    }

    const float da = rsqrtf((float)deg[r0] + 1.0f);
    const float db = rsqrtf((float)deg[r1] + 1.0f);
    dis[r0] = da;
    dis[r1] = db;
    float4* oa = (float4*)(hs1 + (size_t)r0 * H1);
    float4* ob = (float4*)(hs1 + (size_t)r1 * H1);
    #pragma unroll
    for (int q = 0; q < 4; ++q) {
        float4 u, w;
        u.x = acca[4 * q + 0] * da; u.y = acca[4 * q + 1] * da;
        u.z = acca[4 * q + 2] * da; u.w = acca[4 * q + 3] * da;
        w.x = accb[4 * q + 0] * db; w.y = accb[4 * q + 1] * db;
        w.z = accb[4 * q + 2] * db; w.w = accb[4 * q + 3] * db;
        oa[q] = u;
        ob[q] = w;
    }
}

// ---------------------------------------------------------------------------
// Pull aggregation over 16-dim rows: 4-lane group per node, float4 per lane.
// FUSE_L1: c = dis * relu(dis*(acc + hs1_self) + b1) (layer-1 epilogue)
template <int FUSE_L1>
__global__ __launch_bounds__(256) void pull16_kernel(
    const int* __restrict__ row_end, const int* __restrict__ csr,
    const float* __restrict__ rows, const float* __restrict__ dis,
    const float* __restrict__ b1, float* __restrict__ out, int n)
{
    int t = blockIdx.x * 256 + threadIdx.x;
    int g = t >> 2;
    int q = t & 3;
    if (g >= n) return;
    int beg = (g == 0) ? 0 : row_end[g - 1];
    int end = row_end[g];
    float4 acc = make_float4(0.f, 0.f, 0.f, 0.f);
    for (int i = beg; i < end; ++i) {
        int s = csr[i];
        float4 v = ((const float4*)(rows + (size_t)s * H1))[q];
        acc.x += v.x; acc.y += v.y; acc.z += v.z; acc.w += v.w;
    }
    if (FUSE_L1) {
        const float dv = dis[g];
        float4 h = ((const float4*)(rows + (size_t)g * H1))[q];  // self-loop
        float4 bq = ((const float4*)b1)[q];
        acc.x = dv * fmaxf(dv * (acc.x + h.x) + bq.x, 0.f);
        acc.y = dv * fmaxf(dv * (acc.y + h.y) + bq.y, 0.f);
        acc.z = dv * fmaxf(dv * (acc.z + h.z) + bq.z, 0.f);
        acc.w = dv * fmaxf(dv * (acc.w + h.w) + bq.w, 0.f);
    }
    ((float4*)(out + (size_t)g * H1))[q] = acc;
}

// ---------------------------------------------------------------------------
// out[r][j] = log_softmax_j( dis[r] * ((agg2[r]+c[r]) @ W2)[j] + b2[j] )
__global__ __launch_bounds__(256) void epi_kernel(
    const float* __restrict__ agg2, const float* __restrict__ c,
    const float* __restrict__ W2, const float* __restrict__ b2,
    const float* __restrict__ dis, float* __restrict__ out, int n)
{
    __shared__ float w[H1 * H2];
    for (int t = threadIdx.x; t < H1 * H2; t += 256) w[t] = W2[t];
    __syncthreads();

    const int row  = blockIdx.x * 4 + (threadIdx.x >> 6);
    if (row >= n) return;
    const int lane = threadIdx.x & 63;

    float tv = 0.f;
    if (lane < H1)
        tv = agg2[(size_t)row * H1 + lane] + c[(size_t)row * H1 + lane];

    const float dv = dis[row];
    float val = -INFINITY;
    if (lane < H2) {
        float s = 0.f;
        #pragma unroll
        for (int k = 0; k < H1; ++k) {
            float tk = __shfl(tv, k, 64);
            s += tk * w[k * H2 + lane];
        }
        val = dv * s + b2[lane];
    }
    float m = val;
    #pragma unroll
    for (int off = 32; off > 0; off >>= 1) m = fmaxf(m, __shfl_xor(m, off, 64));
    float ex = (lane < H2) ? __expf(val - m) : 0.f;
    #pragma unroll
    for (int off = 32; off > 0; off >>= 1) ex += __shfl_xor(ex, off, 64);
    if (lane < H2) out[(size_t)row * H2 + lane] = val - m - logf(ex);
}

// ---------------------------------------------------------------------------
extern "C" void kernel_launch(void* const* d_in, const int* in_sizes, int n_in,
                              void* d_out, int out_size, void* d_ws, size_t ws_size,
                              hipStream_t stream)
{
    const float* x   = (const float*)d_in[0];
    const void*  ei  = d_in[1];                 // int32 or int64 [2, E] — detected
    const float* W1  = (const float*)d_in[2];
    const float* b1  = (const float*)d_in[3];
    const float* W2  = (const float*)d_in[4];
    const float* b2  = (const float*)d_in[5];
    float*       out = (float*)d_out;

    // workspace layout (4-byte units); ~28.5 MB total, float4-aligned slabs
    int*   base    = (int*)d_ws;
    int*   flag    = base;                                  // 16
    int*   deg     = base + 16;                             // N
    int*   row_end = deg + N_NODES;                         // N
    int*   bstart  = row_end + N_NODES;                     // 512 (NB+1 used)
    int*   cntoff  = bstart + 512;                          // B1*NB = 200192
    float* dis     = (float*)(cntoff + B1 * NB);            // N
    int*   csr     = (int*)(dis + N_NODES);                 // E
    int*   packed  = csr + N_EDGES;                         // E (dead after phase 3)
    float* hs1     = (float*)packed;                        // alias: N*16
    float* c       = hs1 + (size_t)N_NODES * H1;            // alias: N*16
    float* agg2    = hs1;                                   // hs1 dead after pull1

    detect_idx_kernel<<<1, 64, 0, stream>>>((const int*)ei, flag);

    hist_kernel<<<B1, 256, 0, stream>>>(ei, flag, cntoff);
    scanblk_kernel<<<(NB + 3) / 4, 256, 0, stream>>>(cntoff, bstart);
    scanb_kernel<<<1, 512, 0, stream>>>(bstart);
    scatter_bucket_kernel<<<B1, 256, 0, stream>>>(ei, flag, cntoff, bstart, packed);
    bucket_csr_kernel<<<NB, 512, 0, stream>>>(packed, bstart, deg, row_end, csr);

    gemm1_kernel<<<(N_NODES / 2 + 127) / 128, 128, 0, stream>>>(x, W1, deg, hs1, dis, N_NODES);

    const int PB = (N_NODES * 4 + 255) / 256;
    pull16_kernel<1><<<PB, 256, 0, stream>>>(row_end, csr, hs1, dis, b1, c, N_NODES);
    pull16_kernel<0><<<PB, 256, 0, stream>>>(row_end, csr, c, dis, b1, agg2, N_NODES);

    epi_kernel<<<(N_NODES + 3) / 4, 256, 0, stream>>>(agg2, c, W2, b2, dis, out, N_NODES);
}

// Round 8
// 298.021 us; speedup vs baseline: 1.9439x; 1.9439x over previous
//
#include <hip/hip_runtime.h>
#include <math.h>

#define N_NODES 100000
#define N_EDGES 3200000
#define F_IN    512
#define H1      16
#define H2      40

#define NB      391      // coarse buckets: dst >> 8, 256 nodes each
#define BSH     8
#define BMASK   255
#define B1      512      // phase-1/2 blocks
#define EPB     6250     // edges per block (512*6250 = 3.2M exactly)

// ---------------------------------------------------------------------------
// Detect edge_index dtype: int64 (high int32 words all zero) vs int32.
__global__ void detect_idx_kernel(const int* __restrict__ ei, int* __restrict__ flag)
{
    if (threadIdx.x == 0 && blockIdx.x == 0) {
        int all_zero = 1;
        for (int i = 0; i < 64; ++i)
            if (ei[2 * i + 1] != 0) { all_zero = 0; break; }
        *flag = all_zero;  // 1 => int64 layout, 0 => int32 layout
    }
}

__device__ __forceinline__ int edge_src(const void* ei, int e, int is64)
{
    return is64 ? (int)((const long long*)ei)[e] : ((const int*)ei)[e];
}
__device__ __forceinline__ int edge_dst(const void* ei, int e, int is64)
{
    return is64 ? (int)((const long long*)ei)[N_EDGES + e]
                : ((const int*)ei)[N_EDGES + e];
}

// ---------------------------------------------------------------------------
// Phase 1: per-block coarse-bucket histogram (LDS atomics only).
__global__ __launch_bounds__(256) void hist_kernel(
    const void* __restrict__ ei, const int* __restrict__ flag,
    int* __restrict__ cntoff)
{
    __shared__ int h[NB];
    for (int i = threadIdx.x; i < NB; i += 256) h[i] = 0;
    __syncthreads();
    const int is64 = *flag;
    const int e0 = blockIdx.x * EPB;
    for (int i = threadIdx.x; i < EPB; i += 256) {
        int e = e0 + i;
        if (e < N_EDGES) atomicAdd(&h[edge_dst(ei, e, is64) >> BSH], 1);
    }
    __syncthreads();
    for (int i = threadIdx.x; i < NB; i += 256)
        cntoff[blockIdx.x * NB + i] = h[i];
}

// ---------------------------------------------------------------------------
// Phase 1b: per-bucket exclusive scan over the 512 blocks (one wave/bucket).
__global__ __launch_bounds__(256) void scanblk_kernel(
    int* __restrict__ cntoff, int* __restrict__ bstart)
{
    const int lane   = threadIdx.x & 63;
    const int bucket = blockIdx.x * 4 + (threadIdx.x >> 6);
    if (bucket >= NB) return;
    int run = 0;
    #pragma unroll
    for (int c = 0; c < B1 / 64; ++c) {
        const int i = c * 64 + lane;
        const int v = cntoff[i * NB + bucket];
        int s = v;
        #pragma unroll
        for (int off = 1; off < 64; off <<= 1) {
            int t = __shfl_up(s, off, 64);
            if (lane >= off) s += t;
        }
        cntoff[i * NB + bucket] = run + (s - v);   // exclusive within bucket
        run += __shfl(s, 63, 64);
    }
    if (lane == 0) bstart[bucket] = run;
}

// Phase 1c: exclusive scan of the NB bucket totals.
__global__ __launch_bounds__(512) void scanb_kernel(int* __restrict__ bstart)
{
    __shared__ int s[512];
    const int t = threadIdx.x;
    const int v = (t < NB) ? bstart[t] : 0;
    s[t] = v;
    __syncthreads();
    for (int off = 1; off < 512; off <<= 1) {
        int tv = (t >= off) ? s[t - off] : 0;
        __syncthreads();
        s[t] += tv;
        __syncthreads();
    }
    if (t < NB) bstart[t] = s[t] - v;              // exclusive
    if (t == NB - 1) bstart[NB] = s[t];            // total == N_EDGES
}

// ---------------------------------------------------------------------------
// Phase 2: scatter edges into bucket-sorted packed array (LDS cursors only).
// packed = (src << 8) | (dst & 255); src < 2^17 fits easily.
__global__ __launch_bounds__(256) void scatter_bucket_kernel(
    const void* __restrict__ ei, const int* __restrict__ flag,
    const int* __restrict__ cntoff, const int* __restrict__ bstart,
    int* __restrict__ packed)
{
    __shared__ int cur[NB];
    for (int i = threadIdx.x; i < NB; i += 256)
        cur[i] = cntoff[blockIdx.x * NB + i] + bstart[i];
    __syncthreads();
    const int is64 = *flag;
    const int e0 = blockIdx.x * EPB;
    for (int i = threadIdx.x; i < EPB; i += 256) {
        int e = e0 + i;
        if (e >= N_EDGES) break;
        const int s = edge_src(ei, e, is64);
        const int d = edge_dst(ei, e, is64);
        const int b = d >> BSH;
        const int pos = atomicAdd(&cur[b], 1);
        packed[pos] = (s << BSH) | (d & BMASK);
    }
}

// ---------------------------------------------------------------------------
// Phase 3: one block per bucket (256 nodes); fine CSR via LDS hist+scan+scatter.
// row_end[g] = inclusive global prefix; beg(g) = row_end[g-1].
__global__ __launch_bounds__(512) void bucket_csr_kernel(
    const int* __restrict__ packed, const int* __restrict__ bstart,
    int* __restrict__ deg, int* __restrict__ row_end, int* __restrict__ csr)
{
    __shared__ int hist[256];
    __shared__ int off[256];
    const int b    = blockIdx.x;
    const int tid  = threadIdx.x;
    const int base = bstart[b];
    const int m    = bstart[b + 1] - base;

    if (tid < 256) hist[tid] = 0;
    __syncthreads();
    for (int i = tid; i < m; i += 512)
        atomicAdd(&hist[packed[base + i] & BMASK], 1);
    __syncthreads();

    int v = 0;
    if (tid < 256) { v = hist[tid]; off[tid] = v; }
    __syncthreads();
    for (int o = 1; o < 256; o <<= 1) {
        int t2 = 0;
        if (tid < 256 && tid >= o) t2 = off[tid - o];
        __syncthreads();
        if (tid < 256) off[tid] += t2;
        __syncthreads();
    }
    if (tid < 256) {
        const int g = (b << BSH) + tid;
        if (g < N_NODES) { deg[g] = v; row_end[g] = base + off[tid]; }
        off[tid] -= v;                              // exclusive, reuse as cursor
    }
    __syncthreads();
    for (int i = tid; i < m; i += 512) {
        const int p = packed[base + i];
        const int pos = atomicAdd(&off[p & BMASK], 1);
        csr[base + pos] = p >> BSH;
    }
}

// ---------------------------------------------------------------------------
// hs1[r][j] = (x[r] @ W1)[j] * dis[r];  dis[r] = rsqrt(deg[r]+1)
// Thread per row (round-6 structure, measured 87 µs at 256-thread blocks).
// Changes: 64-thread blocks -> 1563 blocks = 6.1 waves/CU, balanced at
// 64-row quanta (round 6's 391x256 grid had ~2x block-quantum imbalance).
// W1 read direct from global at wave-uniform addresses (scalarizable, L1/K$).
__global__ __launch_bounds__(64) void gemm1_kernel(
    const float* __restrict__ x, const float* __restrict__ W1,
    const int* __restrict__ deg, float* __restrict__ hs1,
    float* __restrict__ dis, int n)
{
    const int r = blockIdx.x * 64 + threadIdx.x;
    if (r >= n) return;

    const float4* xr = (const float4*)(x + (size_t)r * F_IN);
    float acc[H1];
    #pragma unroll
    for (int j = 0; j < H1; ++j) acc[j] = 0.f;

    #pragma unroll 4
    for (int k4 = 0; k4 < F_IN / 4; ++k4) {
        const float4 xv = xr[k4];
        const float* wk = W1 + k4 * 4 * H1;        // wave-uniform address
        #pragma unroll
        for (int j = 0; j < H1; ++j)
            acc[j] += xv.x * wk[j] + xv.y * wk[H1 + j]
                    + xv.z * wk[2 * H1 + j] + xv.w * wk[3 * H1 + j];
    }

    const float dv = rsqrtf((float)deg[r] + 1.0f);
    dis[r] = dv;
    float4* o = (float4*)(hs1 + (size_t)r * H1);
    #pragma unroll
    for (int q = 0; q < 4; ++q) {
        float4 v;
        v.x = acc[4 * q + 0] * dv;
        v.y = acc[4 * q + 1] * dv;
        v.z = acc[4 * q + 2] * dv;
        v.w = acc[4 * q + 3] * dv;
        o[q] = v;
    }
}

// ---------------------------------------------------------------------------
// Pull aggregation over 16-dim rows: 4-lane group per node, float4 per lane.
// FUSE_L1: c = dis * relu(dis*(acc + hs1_self) + b1) (layer-1 epilogue)
template <int FUSE_L1>
__global__ __launch_bounds__(256) void pull16_kernel(
    const int* __restrict__ row_end, const int* __restrict__ csr,
    const float* __restrict__ rows, const float* __restrict__ dis,
    const float* __restrict__ b1, float* __restrict__ out, int n)
{
    int t = blockIdx.x * 256 + threadIdx.x;
    int g = t >> 2;
    int q = t & 3;
    if (g >= n) return;
    int beg = (g == 0) ? 0 : row_end[g - 1];
    int end = row_end[g];
    float4 acc = make_float4(0.f, 0.f, 0.f, 0.f);
    for (int i = beg; i < end; ++i) {
        int s = csr[i];
        float4 v = ((const float4*)(rows + (size_t)s * H1))[q];
        acc.x += v.x; acc.y += v.y; acc.z += v.z; acc.w += v.w;
    }
    if (FUSE_L1) {
        const float dv = dis[g];
        float4 h = ((const float4*)(rows + (size_t)g * H1))[q];  // self-loop
        float4 bq = ((const float4*)b1)[q];
        acc.x = dv * fmaxf(dv * (acc.x + h.x) + bq.x, 0.f);
        acc.y = dv * fmaxf(dv * (acc.y + h.y) + bq.y, 0.f);
        acc.z = dv * fmaxf(dv * (acc.z + h.z) + bq.z, 0.f);
        acc.w = dv * fmaxf(dv * (acc.w + h.w) + bq.w, 0.f);
    }
    ((float4*)(out + (size_t)g * H1))[q] = acc;
}

// ---------------------------------------------------------------------------
// out[r][j] = log_softmax_j( dis[r] * ((agg2[r]+c[r]) @ W2)[j] + b2[j] )
__global__ __launch_bounds__(256) void epi_kernel(
    const float* __restrict__ agg2, const float* __restrict__ c,
    const float* __restrict__ W2, const float* __restrict__ b2,
    const float* __restrict__ dis, float* __restrict__ out, int n)
{
    __shared__ float w[H1 * H2];
    for (int t = threadIdx.x; t < H1 * H2; t += 256) w[t] = W2[t];
    __syncthreads();

    const int row  = blockIdx.x * 4 + (threadIdx.x >> 6);
    if (row >= n) return;
    const int lane = threadIdx.x & 63;

    float tv = 0.f;
    if (lane < H1)
        tv = agg2[(size_t)row * H1 + lane] + c[(size_t)row * H1 + lane];

    const float dv = dis[row];
    float val = -INFINITY;
    if (lane < H2) {
        float s = 0.f;
        #pragma unroll
        for (int k = 0; k < H1; ++k) {
            float tk = __shfl(tv, k, 64);
            s += tk * w[k * H2 + lane];
        }
        val = dv * s + b2[lane];
    }
    float m = val;
    #pragma unroll
    for (int off = 32; off > 0; off >>= 1) m = fmaxf(m, __shfl_xor(m, off, 64));
    float ex = (lane < H2) ? __expf(val - m) : 0.f;
    #pragma unroll
    for (int off = 32; off > 0; off >>= 1) ex += __shfl_xor(ex, off, 64);
    if (lane < H2) out[(size_t)row * H2 + lane] = val - m - logf(ex);
}

// ---------------------------------------------------------------------------
extern "C" void kernel_launch(void* const* d_in, const int* in_sizes, int n_in,
                              void* d_out, int out_size, void* d_ws, size_t ws_size,
                              hipStream_t stream)
{
    const float* x   = (const float*)d_in[0];
    const void*  ei  = d_in[1];                 // int32 or int64 [2, E] — detected
    const float* W1  = (const float*)d_in[2];
    const float* b1  = (const float*)d_in[3];
    const float* W2  = (const float*)d_in[4];
    const float* b2  = (const float*)d_in[5];
    float*       out = (float*)d_out;

    // workspace layout (4-byte units); ~28.5 MB total, float4-aligned slabs
    int*   base    = (int*)d_ws;
    int*   flag    = base;                                  // 16
    int*   deg     = base + 16;                             // N
    int*   row_end = deg + N_NODES;                         // N
    int*   bstart  = row_end + N_NODES;                     // 512 (NB+1 used)
    int*   cntoff  = bstart + 512;                          // B1*NB = 200192
    float* dis     = (float*)(cntoff + B1 * NB);            // N
    int*   csr     = (int*)(dis + N_NODES);                 // E
    int*   packed  = csr + N_EDGES;                         // E (dead after phase 3)
    float* hs1     = (float*)packed;                        // alias: N*16
    float* c       = hs1 + (size_t)N_NODES * H1;            // alias: N*16
    float* agg2    = hs1;                                   // hs1 dead after pull1

    detect_idx_kernel<<<1, 64, 0, stream>>>((const int*)ei, flag);

    hist_kernel<<<B1, 256, 0, stream>>>(ei, flag, cntoff);
    scanblk_kernel<<<(NB + 3) / 4, 256, 0, stream>>>(cntoff, bstart);
    scanb_kernel<<<1, 512, 0, stream>>>(bstart);
    scatter_bucket_kernel<<<B1, 256, 0, stream>>>(ei, flag, cntoff, bstart, packed);
    bucket_csr_kernel<<<NB, 512, 0, stream>>>(packed, bstart, deg, row_end, csr);

    gemm1_kernel<<<(N_NODES + 63) / 64, 64, 0, stream>>>(x, W1, deg, hs1, dis, N_NODES);

    const int PB = (N_NODES * 4 + 255) / 256;
    pull16_kernel<1><<<PB, 256, 0, stream>>>(row_end, csr, hs1, dis, b1, c, N_NODES);
    pull16_kernel<0><<<PB, 256, 0, stream>>>(row_end, csr, c, dis, b1, agg2, N_NODES);

    epi_kernel<<<(N_NODES + 3) / 4, 256, 0, stream>>>(agg2, c, W2, b2, dis, out, N_NODES);
}